// Round 4
// baseline (387.801 us; speedup 1.0000x reference)
//
#include <hip/hip_runtime.h>
#include <stdint.h>

#define P_DIM 256
#define NREF  4096
#define NIN   8192
#define DF    512
#define NE    4
#define CREF  1536              // per-element capacity (ref rows)   [mean 1024]
#define CIN   2560              // per-element capacity (query rows) [mean 2048]
#define AE_LD (NE * CREF)       // Ae row stride = 6144
#define NBLK  512               // persistent grid: 2 blocks/CU guaranteed (48KB LDS, LB(256,2))

typedef __bf16 bf16x8 __attribute__((ext_vector_type(8)));
typedef float  f32x4  __attribute__((ext_vector_type(4)));
typedef unsigned short ush8 __attribute__((ext_vector_type(8)));

static __device__ __forceinline__ unsigned short f2bf(float f) {
    uint32_t u = __builtin_bit_cast(uint32_t, f);
    u += 0x7FFFu + ((u >> 16) & 1u);
    return (unsigned short)(u >> 16);
}

// Device-scope grid barrier (G16): all NBLK blocks are resident by construction
// (48KB LDS -> 3 blocks/CU by LDS; __launch_bounds__(256,2) -> >=2 blocks/CU by
// VGPR; grid = 2*256CU). Counter pre-zeroed by plan_sort (runs after poison).
static __device__ __forceinline__ void gridbar(int* b) {
    __syncthreads();
    if (threadIdx.x == 0) {
        __threadfence();   // agent-scope release: flush this XCD's L2 writes
        __hip_atomic_fetch_add(b, 1, __ATOMIC_ACQ_REL, __HIP_MEMORY_SCOPE_AGENT);
        while (__hip_atomic_load(b, __ATOMIC_ACQUIRE, __HIP_MEMORY_SCOPE_AGENT) < NBLK)
            __builtin_amdgcn_s_sleep(2);
    }
    __syncthreads();
}

// Single-block stable counting sort: builds iperm (slot->src row for X_ref),
// jperm (slot->src row for desc), cnt[8]. Also zeroes the grid-barrier slots.
// IMPORTANT: thread t owns the CONTIGUOUS row range [t*CH, (t+1)*CH) so each
// bucket's contents stay nearly sorted ascending -> downstream gathers stream
// X_ref/desc/Alpha almost sequentially. (A "coalesced" t+256k assignment here
// scrambles bucket order and cost ~8us of gather locality — R1/R2 lesson.)
__global__ __launch_bounds__(256) void plan_sort(
    const int* __restrict__ Zr, const int* __restrict__ Z,
    int* __restrict__ iperm, int* __restrict__ jperm, int* __restrict__ cnt,
    int* __restrict__ bar) {
    __shared__ int histX[NE][256];
    __shared__ int histD[NE][256];
    const int t = threadIdx.x;
    constexpr int CHX = NREF / 256;   // 16
    constexpr int CHD = NIN / 256;    // 32

    if (t < 2) bar[t] = 0;            // reset grid-barrier counters (post-poison)

    int lc[NE];
#pragma unroll
    for (int e = 0; e < NE; ++e) lc[e] = 0;
    for (int k = 0; k < CHX; ++k) lc[Zr[t * CHX + k] & (NE - 1)]++;
#pragma unroll
    for (int e = 0; e < NE; ++e) histX[e][t] = lc[e];

#pragma unroll
    for (int e = 0; e < NE; ++e) lc[e] = 0;
    for (int k = 0; k < CHD; ++k) lc[Z[t * CHD + k] & (NE - 1)]++;
#pragma unroll
    for (int e = 0; e < NE; ++e) histD[e][t] = lc[e];

    __syncthreads();
    if (t < 2 * NE) {                  // 8 parallel serial exclusive scans
        int b = t & (NE - 1);
        int isD = t >> 2;
        int run = 0;
        if (!isD) {
            for (int u = 0; u < 256; ++u) { int v = histX[b][u]; histX[b][u] = run; run += v; }
            cnt[b] = run;
        } else {
            for (int u = 0; u < 256; ++u) { int v = histD[b][u]; histD[b][u] = run; run += v; }
            cnt[NE + b] = run;
        }
    }
    __syncthreads();

    int off[NE];
#pragma unroll
    for (int e = 0; e < NE; ++e) off[e] = histX[e][t];
    for (int k = 0; k < CHX; ++k) {
        int i = t * CHX + k;
        int e = Zr[i] & (NE - 1);
        iperm[e * CREF + off[e]++] = i;
    }
#pragma unroll
    for (int e = 0; e < NE; ++e) off[e] = histD[e][t];
    for (int k = 0; k < CHD; ++k) {
        int j = t * CHD + k;
        int e = Z[j] & (NE - 1);
        jperm[e * CIN + off[e]++] = j;
    }
}

#define GATHER_BLOCKS (NE * (CREF + CIN) / 4)      // 4096 vblocks of 4 waves
#define ALPHA_BLOCKS  (P_DIM * AE_LD / (256 * 8))  // 768 vblocks, 8 cols/thread

// Persistent fused kernel: phase A (gather+cast) -> gridbar -> phase B (GEMM1)
// -> gridbar -> phase C (GEMM2+scatter). Phase bodies identical to the
// verified 4-kernel version, only grid-strided. Eliminates 2 launch gaps.
__global__ __launch_bounds__(256, 2) void fused_all(
    const float* __restrict__ Alpha, const float* __restrict__ X_ref,
    const float* __restrict__ desc,
    const int* __restrict__ iperm, const int* __restrict__ jperm,
    const int* __restrict__ cnt,
    unsigned short* __restrict__ Xe, unsigned short* __restrict__ De,
    unsigned short* __restrict__ Ae, unsigned short* __restrict__ KtA,
    float* __restrict__ out, int* __restrict__ bar) {
    constexpr int BK = 64;
    // Union LDS: phase B uses [0,16384); phase C uses [0,24576). 48KB total.
    __shared__ unsigned short lds[24576];

    const int tid = threadIdx.x, wave = tid >> 6, lane = tid & 63;
    const int wr = wave >> 1, wc = wave & 1;
    const int lrow = lane >> 3, ls = lane & 7;
    const int l15 = lane & 15, lq = lane >> 4;

    // ---------------- Phase A: gather + cast ----------------
#pragma unroll 1
    for (int vb = blockIdx.x; vb < GATHER_BLOCKS + ALPHA_BLOCKS; vb += NBLK) {
        if (vb < GATHER_BLOCKS) {
            int w = (vb * 256 + tid) >> 6;
            const float* src = nullptr;
            unsigned short* dstp;
            if (w < NE * CREF) {
                int e = w / CREF, s = w - e * CREF;
                if (s < cnt[e]) src = X_ref + (size_t)iperm[w] * DF;
                dstp = Xe + (size_t)w * DF;
            } else {
                int w2 = w - NE * CREF;
                int e = w2 / CIN, s = w2 - e * CIN;
                if (s < cnt[NE + e]) src = desc + (size_t)jperm[w2] * DF;
                dstp = De + (size_t)w2 * DF;
            }
            ush8 o;
            if (src) {
                float4 a = *(const float4*)(src + lane * 8);
                float4 b = *(const float4*)(src + lane * 8 + 4);
                o[0] = f2bf(a.x); o[1] = f2bf(a.y); o[2] = f2bf(a.z); o[3] = f2bf(a.w);
                o[4] = f2bf(b.x); o[5] = f2bf(b.y); o[6] = f2bf(b.z); o[7] = f2bf(b.w);
            } else {
                o = (ush8){0, 0, 0, 0, 0, 0, 0, 0};
            }
            *(ush8*)(dstp + lane * 8) = o;
        } else {
            // Ae[p][col0..col0+7]; CREF divisible by 8 so 8 cols share one e.
            int idx8 = (vb - GATHER_BLOCKS) * 256 + tid;
            int p = idx8 / (AE_LD / 8);
            int c8 = idx8 - p * (AE_LD / 8);
            int col0 = c8 * 8;
            int e = col0 / CREF;
            int ic0 = col0 - e * CREF;
            int cn = cnt[e];
            const int* ip = iperm + col0;
            ush8 v;
#pragma unroll
            for (int k = 0; k < 8; ++k) {
                unsigned short r = 0;
                if (ic0 + k < cn) r = f2bf(Alpha[(size_t)p * NREF + ip[k]]);
                v[k] = r;
            }
            *(ush8*)(Ae + (size_t)idx8 * 8) = v;
        }
    }

    gridbar(bar + 0);

    // ---------------- Phase B: GEMM1  Kt_e[jl,il] = (De.Xe)^2 ----------------
    {
        unsigned short* tA = lds;           // [128*64]
        unsigned short* tB = lds + 8192;    // [128*64]
#pragma unroll 1
        for (int vt = blockIdx.x; vt < (CREF / 128) * (CIN / 128) * NE; vt += NBLK) {
            const int bx = vt % (CREF / 128);
            const int rem = vt / (CREF / 128);
            const int by = rem % (CIN / 128);
            const int e = rem / (CIN / 128);
            const int padR = (cnt[e] + 127) & ~127;
            const int padI = (cnt[NE + e] + 127) & ~127;
            const int m0 = by * 128;   // jl (query rows)
            const int n0 = bx * 128;   // il (ref rows)
            if (m0 >= padI || n0 >= padR) continue;

            const unsigned short* A = De + (size_t)e * CIN * DF;
            const unsigned short* B = Xe + (size_t)e * CREF * DF;
            unsigned short* C = KtA + (size_t)e * CIN * CREF;

            f32x4 acc[4][4];
#pragma unroll
            for (int r = 0; r < 4; ++r)
#pragma unroll
                for (int c = 0; c < 4; ++c) acc[r][c] = (f32x4){0.f, 0.f, 0.f, 0.f};

            const int waveM = wr * 64, waveN = wc * 64;
#pragma unroll 1
            for (int k0 = 0; k0 < DF; k0 += BK) {
                __syncthreads();
#pragma unroll
                for (int it = 0; it < 8; ++it) {
                    int cb = wave + it * 4;
                    bool isB = cb >= 16;
                    int cb2 = isB ? cb - 16 : cb;
                    int row = cb2 * 8 + lrow;
                    int g = ls ^ (row & 7);
                    const unsigned short* gp = (isB ? B : A)
                        + (size_t)((isB ? n0 : m0) + row) * DF + (size_t)(k0 + g * 8);
                    unsigned short* lp = (isB ? tB : tA) + cb2 * (8 * BK);
                    __builtin_amdgcn_global_load_lds(
                        (const __attribute__((address_space(1))) void*)gp,
                        (__attribute__((address_space(3))) void*)lp, 16, 0, 0);
                }
                __syncthreads();
#pragma unroll
                for (int kk = 0; kk < BK; kk += 32) {
                    const int cbase = kk >> 3;
                    bf16x8 af[4], bfr[4];
#pragma unroll
                    for (int r = 0; r < 4; ++r) {
                        int m = waveM + r * 16 + l15;
                        int ch = (cbase + lq) ^ (m & 7);
                        af[r] = *(const bf16x8*)&tA[m * BK + ch * 8];
                    }
#pragma unroll
                    for (int c = 0; c < 4; ++c) {
                        int n = waveN + c * 16 + l15;
                        int ch = (cbase + lq) ^ (n & 7);
                        bfr[c] = *(const bf16x8*)&tB[n * BK + ch * 8];
                    }
#pragma unroll
                    for (int r = 0; r < 4; ++r)
#pragma unroll
                        for (int c = 0; c < 4; ++c)
                            acc[r][c] = __builtin_amdgcn_mfma_f32_16x16x32_bf16(
                                af[r], bfr[c], acc[r][c], 0, 0, 0);
                }
            }

#pragma unroll
            for (int r = 0; r < 4; ++r) {
                int mb = m0 + waveM + r * 16 + lq * 4;
#pragma unroll
                for (int reg = 0; reg < 4; ++reg) {
                    size_t ro = (size_t)(mb + reg) * CREF;
#pragma unroll
                    for (int c = 0; c < 4; ++c) {
                        int n = n0 + waveN + c * 16 + l15;
                        float v = acc[r][c][reg];
                        C[ro + n] = f2bf(v * v);
                    }
                }
            }
        }
    }

    gridbar(bar + 1);

    // ------- Phase C: GEMM2 + scatter  out[p, jperm[jl]] = Ae . Kt^T -------
    {
        unsigned short* tA2 = lds;            // [2][128*64]
        unsigned short* tB2 = lds + 16384;    // [2][64*64]
#pragma unroll 1
        for (int vt = blockIdx.x; vt < (CIN / 64) * (P_DIM / 128) * NE; vt += NBLK) {
            const int bx = vt % (CIN / 64);
            const int rem = vt / (CIN / 64);
            const int by = rem % (P_DIM / 128);
            const int e = rem / (P_DIM / 128);
            const int cntI = cnt[NE + e];
            const int padR = (cnt[e] + 127) & ~127;
            const int n0 = bx * 64;    // jl
            const int m0 = by * 128;   // p
            if (n0 >= cntI) continue;

            const unsigned short* B = KtA + (size_t)e * CIN * CREF;
            const int waveM = wr * 64, waveN = wc * 32;

            auto stage = [&](int buf, int k0) {
#pragma unroll
                for (int it = 0; it < 6; ++it) {
                    int cb = wave + it * 4;
                    bool isB = cb >= 16;
                    int cb2 = isB ? cb - 16 : cb;
                    int row = cb2 * 8 + lrow;
                    int g = ls ^ (row & 7);
                    const unsigned short* gp = isB
                        ? B + (size_t)(n0 + row) * CREF + (size_t)(k0 + g * 8)
                        : Ae + (size_t)(m0 + row) * AE_LD + (size_t)(e * CREF + k0 + g * 8);
                    unsigned short* lp = (isB ? tB2 + buf * 4096 : tA2 + buf * 8192)
                        + cb2 * (8 * BK);
                    __builtin_amdgcn_global_load_lds(
                        (const __attribute__((address_space(1))) void*)gp,
                        (__attribute__((address_space(3))) void*)lp, 16, 0, 0);
                }
            };

            f32x4 acc[4][2];
#pragma unroll
            for (int r = 0; r < 4; ++r)
#pragma unroll
                for (int c = 0; c < 2; ++c) acc[r][c] = (f32x4){0.f, 0.f, 0.f, 0.f};

            stage(0, 0);
            __syncthreads();
            int buf = 0;
#pragma unroll 1
            for (int k0 = 0; k0 < padR; k0 += BK) {
                if (k0 + BK < padR) stage(buf ^ 1, k0 + BK);
#pragma unroll
                for (int kk = 0; kk < BK; kk += 32) {
                    const int cbase = kk >> 3;
                    bf16x8 af[4], bfr[2];
#pragma unroll
                    for (int r = 0; r < 4; ++r) {
                        int m = waveM + r * 16 + l15;
                        int ch = (cbase + lq) ^ (m & 7);
                        af[r] = *(const bf16x8*)&tA2[buf * 8192 + m * BK + ch * 8];
                    }
#pragma unroll
                    for (int c = 0; c < 2; ++c) {
                        int n = waveN + c * 16 + l15;
                        int ch = (cbase + lq) ^ (n & 7);
                        bfr[c] = *(const bf16x8*)&tB2[buf * 4096 + n * BK + ch * 8];
                    }
#pragma unroll
                    for (int r = 0; r < 4; ++r)
#pragma unroll
                        for (int c = 0; c < 2; ++c)
                            acc[r][c] = __builtin_amdgcn_mfma_f32_16x16x32_bf16(
                                af[r], bfr[c], acc[r][c], 0, 0, 0);
                }
                __syncthreads();
                buf ^= 1;
            }

            int jok[2], jdest[2];
#pragma unroll
            for (int c = 0; c < 2; ++c) {
                int jl = n0 + waveN + c * 16 + l15;
                jok[c] = jl < cntI;
                jdest[c] = jok[c] ? jperm[e * CIN + jl] : 0;
            }
#pragma unroll
            for (int r = 0; r < 4; ++r) {
                int pb = m0 + waveM + r * 16 + lq * 4;
#pragma unroll
                for (int reg = 0; reg < 4; ++reg) {
                    size_t ro = (size_t)(pb + reg) * NIN;
#pragma unroll
                    for (int c = 0; c < 2; ++c)
                        if (jok[c]) out[ro + jdest[c]] = acc[r][c][reg];
                }
            }
        }
    }
}

extern "C" void kernel_launch(void* const* d_in, const int* in_sizes, int n_in,
                              void* d_out, int out_size, void* d_ws, size_t ws_size,
                              hipStream_t stream) {
    const float* Alpha = (const float*)d_in[0];   // [256, 4096]
    const float* X_ref = (const float*)d_in[1];   // [4096, 512]
    const float* desc  = (const float*)d_in[2];   // [8192, 512]
    const int*   Z_ref = (const int*)d_in[3];     // [4096]
    const int*   Z     = (const int*)d_in[4];     // [8192]
    float* out = (float*)d_out;                   // [256, 8192]

    // ws (ushort units): Xe 6.3MB | De 10.5MB | Ae 3.1MB | Kt 31.5MB | perms/cnt/bar
    unsigned short* Xe = (unsigned short*)d_ws;            // NE*CREF*DF
    unsigned short* De = Xe + (size_t)NE * CREF * DF;      // NE*CIN*DF
    unsigned short* Ae = De + (size_t)NE * CIN * DF;       // P_DIM*AE_LD
    unsigned short* Kt = Ae + (size_t)P_DIM * AE_LD;       // NE*CIN*CREF
    int* iperm = (int*)(Kt + (size_t)NE * CIN * CREF);     // NE*CREF
    int* jperm = iperm + NE * CREF;                        // NE*CIN
    int* cnt   = jperm + NE * CIN;                         // 8
    int* bar   = cnt + 8;                                  // 2 grid-barrier slots

    plan_sort<<<1, 256, 0, stream>>>(Z_ref, Z, iperm, jperm, cnt, bar);

    fused_all<<<NBLK, 256, 0, stream>>>(Alpha, X_ref, desc, iperm, jperm, cnt,
                                        Xe, De, Ae, Kt, out, bar);
}

// Round 5
// 150.909 us; speedup vs baseline: 2.5698x; 2.5698x over previous
//
#include <hip/hip_runtime.h>
#include <stdint.h>

#define P_DIM 256
#define NREF  4096
#define NIN   8192
#define DF    512
#define NE    4
#define CREF  1536              // per-element capacity (ref rows)   [mean 1024]
#define CIN   2560              // per-element capacity (query rows) [mean 2048]
#define AE_LD (NE * CREF)       // Ae row stride = 6144

typedef __bf16 bf16x8 __attribute__((ext_vector_type(8)));
typedef float  f32x4  __attribute__((ext_vector_type(4)));
typedef unsigned short ush8 __attribute__((ext_vector_type(8)));

static __device__ __forceinline__ unsigned short f2bf(float f) {
    uint32_t u = __builtin_bit_cast(uint32_t, f);
    u += 0x7FFFu + ((u >> 16) & 1u);
    return (unsigned short)(u >> 16);
}

// Single-block stable counting sort: builds iperm (slot->src row for X_ref),
// jperm (slot->src row for desc), cnt[8]. No global atomics.
// ORDER LESSON (R1/R2): thread t owns the CONTIGUOUS row range [t*CH,(t+1)*CH)
// so each bucket stays nearly sorted ascending -> downstream gathers stream
// X_ref/desc/Alpha almost sequentially (a strided assignment cost ~8us).
// SCAN LESSON (R4): the old 256-iteration serial LDS scan was ~5-8us of
// dependent LDS round-trips; replaced by a wave-parallel __shfl_up scan over
// register-held counts + tiny cross-wave LDS fixup. Same stable output.
__global__ __launch_bounds__(256) void plan_sort(
    const int* __restrict__ Zr, const int* __restrict__ Z,
    int* __restrict__ iperm, int* __restrict__ jperm, int* __restrict__ cnt) {
    const int t = threadIdx.x;
    const int lane = t & 63, wv = t >> 6;
    constexpr int CHX = NREF / 256;   // 16
    constexpr int CHD = NIN / 256;    // 32

    __shared__ int wpart[2][NE][4];   // [X/D][bucket][wave] inclusive totals

    // Per-thread bucket counts, Z values cached in registers (static indexing
    // only — runtime-indexed register arrays go to scratch, rule #20).
    int zx[CHX], zd[CHD];
    int cx[NE], cd[NE];
#pragma unroll
    for (int e = 0; e < NE; ++e) { cx[e] = 0; cd[e] = 0; }
#pragma unroll
    for (int k = 0; k < CHX; ++k) {
        zx[k] = Zr[t * CHX + k] & (NE - 1);
#pragma unroll
        for (int e = 0; e < NE; ++e) cx[e] += (zx[k] == e);
    }
#pragma unroll
    for (int k = 0; k < CHD; ++k) {
        zd[k] = Z[t * CHD + k] & (NE - 1);
#pragma unroll
        for (int e = 0; e < NE; ++e) cd[e] += (zd[k] == e);
    }

    // Inclusive intra-wave scan of the 8 count streams (6 shfl steps).
    int sx[NE], sd[NE];
#pragma unroll
    for (int e = 0; e < NE; ++e) { sx[e] = cx[e]; sd[e] = cd[e]; }
#pragma unroll
    for (int d = 1; d < 64; d <<= 1) {
#pragma unroll
        for (int e = 0; e < NE; ++e) {
            int ux = __shfl_up(sx[e], d, 64);
            int ud = __shfl_up(sd[e], d, 64);
            if (lane >= d) { sx[e] += ux; sd[e] += ud; }
        }
    }
    if (lane == 63) {
#pragma unroll
        for (int e = 0; e < NE; ++e) { wpart[0][e][wv] = sx[e]; wpart[1][e][wv] = sd[e]; }
    }
    __syncthreads();

    // Exclusive offset for this thread = inclusive - own + prior-wave totals.
#pragma unroll
    for (int e = 0; e < NE; ++e) {
        int ox = 0, od = 0;
#pragma unroll
        for (int w2 = 0; w2 < 4; ++w2) {
            if (w2 < wv) { ox += wpart[0][e][w2]; od += wpart[1][e][w2]; }
        }
        sx[e] += ox - cx[e];
        sd[e] += od - cd[e];
    }

    if (t < 2 * NE) {
        int b = t & (NE - 1);
        int isD = t >> 2;
        cnt[t] = wpart[isD][b][0] + wpart[isD][b][1]
               + wpart[isD][b][2] + wpart[isD][b][3];
    }

    // Stable scatter, same order as the serial version (chunk-contiguous).
#pragma unroll
    for (int k = 0; k < CHX; ++k) {
        int i = t * CHX + k;
#pragma unroll
        for (int e = 0; e < NE; ++e)
            if (zx[k] == e) { iperm[e * CREF + sx[e]] = i; sx[e]++; }
    }
#pragma unroll
    for (int k = 0; k < CHD; ++k) {
        int j = t * CHD + k;
#pragma unroll
        for (int e = 0; e < NE; ++e)
            if (zd[k] == e) { jperm[e * CIN + sd[e]] = j; sd[e]++; }
    }
}

#define GATHER_BLOCKS (NE * (CREF + CIN) / 4)      // 4096 blocks of 4 waves
#define ALPHA_BLOCKS  (P_DIM * AE_LD / (256 * 8))  // 768 blocks, 8 cols/thread

// Fused gather: blocks [0, GATHER_BLOCKS) do the X_ref/desc row gather+cast
// (one wave per destination slot, pad slots -> zeros). Blocks after that do
// the Alpha column gather into Ae (vectorized ush8 stores).
__global__ void gather_all(const float* __restrict__ Alpha,
                           const float* __restrict__ X_ref, const float* __restrict__ desc,
                           const int* __restrict__ iperm, const int* __restrict__ jperm,
                           const int* __restrict__ cnt,
                           unsigned short* __restrict__ Xe, unsigned short* __restrict__ De,
                           unsigned short* __restrict__ Ae) {
    if (blockIdx.x < GATHER_BLOCKS) {
        int w = (blockIdx.x * blockDim.x + threadIdx.x) >> 6;
        int lane = threadIdx.x & 63;
        const float* src = nullptr;
        unsigned short* dstp;
        if (w < NE * CREF) {
            int e = w / CREF, s = w - e * CREF;
            if (s < cnt[e]) src = X_ref + (size_t)iperm[w] * DF;
            dstp = Xe + (size_t)w * DF;
        } else {
            int w2 = w - NE * CREF;
            int e = w2 / CIN, s = w2 - e * CIN;
            if (s < cnt[NE + e]) src = desc + (size_t)jperm[w2] * DF;
            dstp = De + (size_t)w2 * DF;
        }
        ush8 o;
        if (src) {
            float4 a = *(const float4*)(src + lane * 8);
            float4 b = *(const float4*)(src + lane * 8 + 4);
            o[0] = f2bf(a.x); o[1] = f2bf(a.y); o[2] = f2bf(a.z); o[3] = f2bf(a.w);
            o[4] = f2bf(b.x); o[5] = f2bf(b.y); o[6] = f2bf(b.z); o[7] = f2bf(b.w);
        } else {
            o = (ush8){0, 0, 0, 0, 0, 0, 0, 0};
        }
        *(ush8*)(dstp + lane * 8) = o;
    } else {
        // Ae[p][col0..col0+7]; CREF divisible by 8 so the 8 cols share one e.
        int idx8 = (blockIdx.x - GATHER_BLOCKS) * 256 + threadIdx.x;
        int p = idx8 / (AE_LD / 8);
        int c8 = idx8 - p * (AE_LD / 8);
        int col0 = c8 * 8;
        int e = col0 / CREF;
        int ic0 = col0 - e * CREF;
        int cn = cnt[e];
        const int* ip = iperm + col0;
        ush8 v;
#pragma unroll
        for (int k = 0; k < 8; ++k) {
            unsigned short r = 0;
            if (ic0 + k < cn) r = f2bf(Alpha[(size_t)p * NREF + ip[k]]);
            v[k] = r;
        }
        *(ush8*)(Ae + (size_t)idx8 * 8) = v;
    }
}

// Per-element GEMM1: Kt_e[jl, il] = (De_jl . Xe_il)^2  (bf16, row stride CREF).
// Single-buffered (32KB LDS): at ~2+ blocks/CU the cross-block wave overlap
// already hides the stage latency (m114); 64KB dbuf costs occupancy (m132).
__global__ __launch_bounds__(256) void g1_grouped(
    const unsigned short* __restrict__ DeA, const unsigned short* __restrict__ XeA,
    unsigned short* __restrict__ KtA, const int* __restrict__ cnt) {
    constexpr int BK = 64;
    const int e = blockIdx.z;
    const int padR = (cnt[e] + 127) & ~127;
    const int padI = (cnt[NE + e] + 127) & ~127;
    const int m0 = blockIdx.y * 128;   // jl (query rows)
    const int n0 = blockIdx.x * 128;   // il (ref rows)
    if (m0 >= padI || n0 >= padR) return;

    const unsigned short* A = DeA + (size_t)e * CIN * DF;
    const unsigned short* B = XeA + (size_t)e * CREF * DF;
    unsigned short* C = KtA + (size_t)e * CIN * CREF;

    __shared__ unsigned short tA[128 * BK];
    __shared__ unsigned short tB[128 * BK];

    const int tid = threadIdx.x, wave = tid >> 6, lane = tid & 63;
    const int wr = wave >> 1, wc = wave & 1;
    const int waveM = wr * 64, waveN = wc * 64;
    const int lrow = lane >> 3, ls = lane & 7;
    const int l15 = lane & 15, lq = lane >> 4;

    f32x4 acc[4][4];
#pragma unroll
    for (int r = 0; r < 4; ++r)
#pragma unroll
        for (int c = 0; c < 4; ++c) acc[r][c] = (f32x4){0.f, 0.f, 0.f, 0.f};

#pragma unroll 1
    for (int k0 = 0; k0 < DF; k0 += BK) {
        __syncthreads();
#pragma unroll
        for (int it = 0; it < 8; ++it) {
            int cb = wave + it * 4;
            bool isB = cb >= 16;
            int cb2 = isB ? cb - 16 : cb;
            int row = cb2 * 8 + lrow;
            int g = ls ^ (row & 7);
            const unsigned short* gp = (isB ? B : A)
                + (size_t)((isB ? n0 : m0) + row) * DF + (size_t)(k0 + g * 8);
            unsigned short* lp = (isB ? tB : tA) + cb2 * (8 * BK);
            __builtin_amdgcn_global_load_lds(
                (const __attribute__((address_space(1))) void*)gp,
                (__attribute__((address_space(3))) void*)lp, 16, 0, 0);
        }
        __syncthreads();
#pragma unroll
        for (int kk = 0; kk < BK; kk += 32) {
            const int cbase = kk >> 3;
            bf16x8 af[4], bfr[4];
#pragma unroll
            for (int r = 0; r < 4; ++r) {
                int m = waveM + r * 16 + l15;
                int ch = (cbase + lq) ^ (m & 7);
                af[r] = *(const bf16x8*)&tA[m * BK + ch * 8];
            }
#pragma unroll
            for (int c = 0; c < 4; ++c) {
                int n = waveN + c * 16 + l15;
                int ch = (cbase + lq) ^ (n & 7);
                bfr[c] = *(const bf16x8*)&tB[n * BK + ch * 8];
            }
#pragma unroll
            for (int r = 0; r < 4; ++r)
#pragma unroll
                for (int c = 0; c < 4; ++c)
                    acc[r][c] = __builtin_amdgcn_mfma_f32_16x16x32_bf16(
                        af[r], bfr[c], acc[r][c], 0, 0, 0);
        }
    }

#pragma unroll
    for (int r = 0; r < 4; ++r) {
        int mb = m0 + waveM + r * 16 + lq * 4;
#pragma unroll
        for (int reg = 0; reg < 4; ++reg) {
            size_t ro = (size_t)(mb + reg) * CREF;
#pragma unroll
            for (int c = 0; c < 4; ++c) {
                int n = n0 + waveN + c * 16 + l15;
                float v = acc[r][c][reg];
                C[ro + n] = f2bf(v * v);
            }
        }
    }
}

// Per-element GEMM2 + scatter: out[p, jperm[jl]] = sum_il Ae[p,il] * Kt_e[jl,il].
// 2-phase double-buffered (48KB LDS): this kernel runs at ~1 block/CU so
// intra-block load/MFMA overlap is the only latency hiding available.
__global__ __launch_bounds__(256) void g2_grouped(
    const unsigned short* __restrict__ Ae, const unsigned short* __restrict__ KtA,
    const int* __restrict__ jperm, const int* __restrict__ cnt,
    float* __restrict__ out) {
    constexpr int BK = 64;
    const int e = blockIdx.z;
    const int cntI = cnt[NE + e];
    const int padR = (cnt[e] + 127) & ~127;
    const int n0 = blockIdx.x * 64;    // jl
    const int m0 = blockIdx.y * 128;   // p
    if (n0 >= cntI) return;

    const unsigned short* B = KtA + (size_t)e * CIN * CREF;

    __shared__ unsigned short tA[2][128 * BK];
    __shared__ unsigned short tB[2][64 * BK];

    const int tid = threadIdx.x, wave = tid >> 6, lane = tid & 63;
    const int wr = wave >> 1, wc = wave & 1;
    const int waveM = wr * 64, waveN = wc * 32;
    const int lrow = lane >> 3, ls = lane & 7;
    const int l15 = lane & 15, lq = lane >> 4;

    auto stage = [&](int buf, int k0) {
#pragma unroll
        for (int it = 0; it < 6; ++it) {
            int cb = wave + it * 4;
            bool isB = cb >= 16;
            int cb2 = isB ? cb - 16 : cb;
            int row = cb2 * 8 + lrow;
            int g = ls ^ (row & 7);
            const unsigned short* gp = isB
                ? B + (size_t)(n0 + row) * CREF + (size_t)(k0 + g * 8)
                : Ae + (size_t)(m0 + row) * AE_LD + (size_t)(e * CREF + k0 + g * 8);
            unsigned short* lp = (isB ? tB[buf] : tA[buf]) + cb2 * (8 * BK);
            __builtin_amdgcn_global_load_lds(
                (const __attribute__((address_space(1))) void*)gp,
                (__attribute__((address_space(3))) void*)lp, 16, 0, 0);
        }
    };

    f32x4 acc[4][2];
#pragma unroll
    for (int r = 0; r < 4; ++r)
#pragma unroll
        for (int c = 0; c < 2; ++c) acc[r][c] = (f32x4){0.f, 0.f, 0.f, 0.f};

    if (padR > 0) {
        stage(0, 0);
        __syncthreads();
        int buf = 0;
#pragma unroll 1
        for (int k0 = 0; k0 < padR; k0 += BK) {
            if (k0 + BK < padR) stage(buf ^ 1, k0 + BK);
#pragma unroll
            for (int kk = 0; kk < BK; kk += 32) {
                const int cbase = kk >> 3;
                bf16x8 af[4], bfr[2];
#pragma unroll
                for (int r = 0; r < 4; ++r) {
                    int m = waveM + r * 16 + l15;
                    int ch = (cbase + lq) ^ (m & 7);
                    af[r] = *(const bf16x8*)&tA[buf][m * BK + ch * 8];
                }
#pragma unroll
                for (int c = 0; c < 2; ++c) {
                    int n = waveN + c * 16 + l15;
                    int ch = (cbase + lq) ^ (n & 7);
                    bfr[c] = *(const bf16x8*)&tB[buf][n * BK + ch * 8];
                }
#pragma unroll
                for (int r = 0; r < 4; ++r)
#pragma unroll
                    for (int c = 0; c < 2; ++c)
                        acc[r][c] = __builtin_amdgcn_mfma_f32_16x16x32_bf16(
                            af[r], bfr[c], acc[r][c], 0, 0, 0);
            }
            __syncthreads();
            buf ^= 1;
        }
    }

    int jok[2], jdest[2];
#pragma unroll
    for (int c = 0; c < 2; ++c) {
        int jl = n0 + waveN + c * 16 + l15;
        jok[c] = jl < cntI;
        jdest[c] = jok[c] ? jperm[e * CIN + jl] : 0;
    }
#pragma unroll
    for (int r = 0; r < 4; ++r) {
        int pb = m0 + waveM + r * 16 + lq * 4;
#pragma unroll
        for (int reg = 0; reg < 4; ++reg) {
            size_t ro = (size_t)(pb + reg) * NIN;
#pragma unroll
            for (int c = 0; c < 2; ++c)
                if (jok[c]) out[ro + jdest[c]] = acc[r][c][reg];
        }
    }
}

extern "C" void kernel_launch(void* const* d_in, const int* in_sizes, int n_in,
                              void* d_out, int out_size, void* d_ws, size_t ws_size,
                              hipStream_t stream) {
    const float* Alpha = (const float*)d_in[0];   // [256, 4096]
    const float* X_ref = (const float*)d_in[1];   // [4096, 512]
    const float* desc  = (const float*)d_in[2];   // [8192, 512]
    const int*   Z_ref = (const int*)d_in[3];     // [4096]
    const int*   Z     = (const int*)d_in[4];     // [8192]
    float* out = (float*)d_out;                   // [256, 8192]

    // ws (ushort units): Xe 6.3MB | De 10.5MB | Ae 3.1MB | Kt 31.5MB | perms/cnt
    unsigned short* Xe = (unsigned short*)d_ws;            // NE*CREF*DF
    unsigned short* De = Xe + (size_t)NE * CREF * DF;      // NE*CIN*DF
    unsigned short* Ae = De + (size_t)NE * CIN * DF;       // P_DIM*AE_LD
    unsigned short* Kt = Ae + (size_t)P_DIM * AE_LD;       // NE*CIN*CREF
    int* iperm = (int*)(Kt + (size_t)NE * CIN * CREF);     // NE*CREF
    int* jperm = iperm + NE * CREF;                        // NE*CIN
    int* cnt   = jperm + NE * CIN;                         // 8

    plan_sort<<<1, 256, 0, stream>>>(Z_ref, Z, iperm, jperm, cnt);

    gather_all<<<GATHER_BLOCKS + ALPHA_BLOCKS, 256, 0, stream>>>(
        Alpha, X_ref, desc, iperm, jperm, cnt, Xe, De, Ae);

    g1_grouped<<<dim3(CREF / 128, CIN / 128, NE), 256, 0, stream>>>(De, Xe, Kt, cnt);

    g2_grouped<<<dim3(CIN / 64, P_DIM / 128, NE), 256, 0, stream>>>(Ae, Kt, jperm, cnt, out);
}